// Round 6
// baseline (250.364 us; speedup 1.0000x reference)
//
#include <hip/hip_runtime.h>
#include <hip/hip_bf16.h>
#include <math.h>

#define BB 8
#define NN 2048
#define DD 128
#define ALPHA 0.2f
#define LOG2E 1.4426950408889634f

typedef __attribute__((ext_vector_type(8))) short short8;
typedef __attribute__((ext_vector_type(4))) float f32x4;

__device__ inline unsigned short bf16_rne(float v) {
    unsigned int x = __float_as_uint(v);
    unsigned int r = x + 0x7FFFu + ((x >> 16) & 1u);
    return (unsigned short)(r >> 16);
}

// ---------------- Kernel 0: adj (int32 0/1) -> bitmask, pure HBM stream ----------------
__global__ __launch_bounds__(256) void bitpack_kernel(const int* __restrict__ adj,
                                                      unsigned* __restrict__ bits) {
    unsigned g0 = blockIdx.x * 256 + threadIdx.x;
#pragma unroll
    for (int rep = 0; rep < 2; ++rep) {
        unsigned g = g0 + rep * 524288u;           // 1048576 words total
        const int4* p = reinterpret_cast<const int4*>(adj + (size_t)g * 32);
        int4 v[8];
#pragma unroll
        for (int i = 0; i < 8; ++i) v[i] = p[i];   // 8x16B in flight
        unsigned w = 0;
#pragma unroll
        for (int i = 0; i < 8; ++i) {              // adj values are exactly 0/1
            w |= ((unsigned)v[i].x) << (4 * i);
            w |= ((unsigned)v[i].y) << (4 * i + 1);
            w |= ((unsigned)v[i].z) << (4 * i + 2);
            w |= ((unsigned)v[i].w) << (4 * i + 3);
        }
        bits[g] = w;
    }
}

// ---------------- Kernel 1: f1/f2 scores (pre-scaled by log2e) + bf16 H^T panel ----------------
// Panel layout (per batch): [ks=0..63][n=0..127][c=0..3][e=0..7] bf16, elem = h[ks*32+c*8+e][n]
__global__ __launch_bounds__(256) void pack_kernel(const float* __restrict__ h,
                                                   const float* __restrict__ a1,
                                                   const float* __restrict__ a2,
                                                   float* __restrict__ f1,
                                                   float* __restrict__ f2,
                                                   unsigned short* __restrict__ panel) {
    __shared__ float hs[32][DD];   // 16 KB
    int blk = blockIdx.x;
    int b   = blk >> 6;
    int ks  = blk & 63;
    int r0  = ks * 32;
    int t   = threadIdx.x;

    const float* hb = h + ((size_t)b * NN + r0) * DD;
#pragma unroll
    for (int m = 0; m < 4; ++m) {
        int off = t * 4 + m * 1024;
        *reinterpret_cast<float4*>(&hs[0][0] + off) =
            *reinterpret_cast<const float4*>(hb + off);
    }
    __syncthreads();

    {
        int row = t >> 3, d0 = (t & 7) * 16;
        float s1 = 0.f, s2 = 0.f;
#pragma unroll
        for (int q = 0; q < 4; ++q) {
            float4 hv  = *reinterpret_cast<const float4*>(&hs[row][d0 + q * 4]);
            float4 av1 = *reinterpret_cast<const float4*>(a1 + d0 + q * 4);
            float4 av2 = *reinterpret_cast<const float4*>(a2 + d0 + q * 4);
            s1 += hv.x * av1.x + hv.y * av1.y + hv.z * av1.z + hv.w * av1.w;
            s2 += hv.x * av2.x + hv.y * av2.y + hv.z * av2.z + hv.w * av2.w;
        }
#pragma unroll
        for (int off = 1; off < 8; off <<= 1) {
            s1 += __shfl_xor(s1, off, 64);
            s2 += __shfl_xor(s2, off, 64);
        }
        if ((t & 7) == 0) {
            f1[b * NN + r0 + row] = s1 * LOG2E;   // exp(lrelu(x)) == exp2(lrelu(x*log2e))
            f2[b * NN + r0 + row] = s2 * LOG2E;
        }
    }

    {
        int n = t >> 1;
        size_t base = (((size_t)b * 64 + ks) * 128 + n) * 32;
#pragma unroll
        for (int cc = 0; cc < 2; ++cc) {
            int c = (t & 1) * 2 + cc;
            short8 v;
#pragma unroll
            for (int e = 0; e < 8; ++e) v[e] = (short)bf16_rne(hs[c * 8 + e][n]);
            *reinterpret_cast<short8*>(panel + base + (size_t)c * 8) = v;
        }
    }
}

// ---------------- Kernel 2: W-gen (regs) + MFMA aggregation, L2-only traffic ----------------
// Block: 16 rows, 4 waves each own a K-quarter (512). Denominator via ones-column MFMA.
// unroll 2 + (256,3): no spills (round-4/5 lesson: full unroll at (256,4) spilled, WRITE 48MB)
__global__ __launch_bounds__(256, 3) void gat_mfma(const unsigned* __restrict__ bits,
                                                   const float* __restrict__ f1,
                                                   const float* __restrict__ f2,
                                                   const unsigned short* __restrict__ panel,
                                                   float* __restrict__ out) {
    __shared__ float buf[2][16][132];   // 16896 B
    __shared__ float sden[4][16];

    int blk  = blockIdx.x;
    int b    = blk & 7;        // XCD-aligned batch (1024 % 8 == 0)
    int tile = blk >> 3;
    int i0   = tile * 16;
    int t    = threadIdx.x;
    int w    = t >> 6, l = t & 63;
    int lr   = l & 15, lc = l >> 4;

    const unsigned short* pb = panel + (size_t)b * (64 * 128 * 32);
    const float* f2b = f2 + b * NN;
    float f1r = f1[b * NN + i0 + lr];

    int kbase = w * 512;
    const unsigned* brow = bits + (((size_t)(b * NN + i0 + lr)) << 6) + (kbase >> 5);

    f32x4 acc[8];
#pragma unroll
    for (int nt = 0; nt < 8; ++nt) acc[nt] = (f32x4){0.f, 0.f, 0.f, 0.f};
    f32x4 accd = (f32x4){0.f, 0.f, 0.f, 0.f};

    short8 ones;
#pragma unroll
    for (int e = 0; e < 8; ++e) ones[e] = (short)0x3F80;   // bf16 1.0

    // 1-iter-ahead prefetch state (bits + f2)
    unsigned bcur = brow[0];
    float4 g0c = *reinterpret_cast<const float4*>(f2b + kbase + lc * 8);
    float4 g1c = *reinterpret_cast<const float4*>(f2b + kbase + lc * 8 + 4);

#pragma unroll 2
    for (int ks = 0; ks < 16; ++ks) {
        int k0 = kbase + ks * 32;
        unsigned bs = bcur >> (lc * 8);
        float4 g0 = g0c, g1 = g1c;

        // panel fragments for this iter (L2-resident; W-gen VALU covers latency)
        const unsigned short* pk = pb + (size_t)(k0 >> 5) * 4096 + lr * 32 + lc * 8;
        short8 bf[8];
#pragma unroll
        for (int nt = 0; nt < 8; ++nt)
            bf[nt] = *reinterpret_cast<const short8*>(pk + nt * 512);

        // prefetch next iter's bits/f2
        if (ks < 15) {
            bcur = brow[ks + 1];
            int jn = k0 + 32 + lc * 8;
            g0c = *reinterpret_cast<const float4*>(f2b + jn);
            g1c = *reinterpret_cast<const float4*>(f2b + jn + 4);
        }

        float f2v[8] = {g0.x, g0.y, g0.z, g0.w, g1.x, g1.y, g1.z, g1.w};
        float wv[8];
#pragma unroll
        for (int e = 0; e < 8; ++e) {
            float x  = f1r + f2v[e];
            float ee = fmaxf(x, ALPHA * x);
            float gv = __builtin_amdgcn_exp2f(ee);
            wv[e] = ((bs >> e) & 1u) ? gv : 0.f;
        }
        union { short8 s; __hip_bfloat162 h2[4]; } u;
#pragma unroll
        for (int p = 0; p < 4; ++p)
            u.h2[p] = __float22bfloat162_rn(make_float2(wv[2 * p], wv[2 * p + 1]));

#pragma unroll
        for (int nt = 0; nt < 8; ++nt)
            acc[nt] = __builtin_amdgcn_mfma_f32_16x16x32_bf16(u.s, bf[nt], acc[nt], 0, 0, 0);
        accd = __builtin_amdgcn_mfma_f32_16x16x32_bf16(u.s, ones, accd, 0, 0, 0);
    }

    // denominator: D[i][n] identical over n; lanes with col==0 hold rows (l>>4)*4+r
    if ((l & 15) == 0) {
#pragma unroll
        for (int r = 0; r < 4; ++r) sden[w][(l >> 4) * 4 + r] = accd[r];
    }

    // cross-wave K reduction: pair (0,1)->buf0, (2,3)->buf1
    float* mybuf = &buf[w >> 1][0][0];
    if ((w & 1) == 0) {
#pragma unroll
        for (int nt = 0; nt < 8; ++nt) {
            float* p = mybuf + (lc * 4) * 132 + nt * 16 + lr;
#pragma unroll
            for (int r = 0; r < 4; ++r) p[r * 132] = acc[nt][r];
        }
    }
    __syncthreads();
    if (w & 1) {
#pragma unroll
        for (int nt = 0; nt < 8; ++nt) {
            float* p = mybuf + (lc * 4) * 132 + nt * 16 + lr;
#pragma unroll
            for (int r = 0; r < 4; ++r) p[r * 132] += acc[nt][r];
        }
    }
    __syncthreads();

    // epilogue: row t>>4, cols (t&15)*8..+8 ; out = elu((buf0+buf1)/den)
    {
        int row = t >> 4, col0 = (t & 15) * 8;
        float den = sden[0][row] + sden[1][row] + sden[2][row] + sden[3][row];
        float inv = 1.0f / den;
        float* ob = out + ((size_t)b * NN + i0 + row) * DD;
#pragma unroll
        for (int q = 0; q < 2; ++q) {
            int col = col0 + q * 4;
            float4 v0 = *reinterpret_cast<const float4*>(&buf[0][row][col]);
            float4 v1 = *reinterpret_cast<const float4*>(&buf[1][row][col]);
            float r0 = (v0.x + v1.x) * inv;
            float r1 = (v0.y + v1.y) * inv;
            float r2 = (v0.z + v1.z) * inv;
            float r3 = (v0.w + v1.w) * inv;
            r0 = (r0 > 0.f) ? r0 : expm1f(r0);
            r1 = (r1 > 0.f) ? r1 : expm1f(r1);
            r2 = (r2 > 0.f) ? r2 : expm1f(r2);
            r3 = (r3 > 0.f) ? r3 : expm1f(r3);
            *reinterpret_cast<float4*>(ob + col) = make_float4(r0, r1, r2, r3);
        }
    }
}

extern "C" void kernel_launch(void* const* d_in, const int* in_sizes, int n_in,
                              void* d_out, int out_size, void* d_ws, size_t ws_size,
                              hipStream_t stream) {
    const float* h   = (const float*)d_in[0];
    const int*   adj = (const int*)d_in[1];
    const float* a1  = (const float*)d_in[2];
    const float* a2  = (const float*)d_in[3];
    float* out = (float*)d_out;

    float* f1 = (float*)d_ws;                                   // 16384 floats
    float* f2 = f1 + BB * NN;                                   // 16384 floats
    unsigned short* panel = (unsigned short*)(f2 + BB * NN);    // 4 MB
    unsigned* bits = (unsigned*)(panel + (size_t)BB * 64 * 128 * 32);  // 4 MB

    bitpack_kernel<<<2048, 256, 0, stream>>>(adj, bits);
    pack_kernel<<<BB * 64, 256, 0, stream>>>(h, a1, a2, f1, f2, panel);
    gat_mfma<<<BB * 128, 256, 0, stream>>>(bits, f1, f2, panel, out);
}

// Round 7
// 241.425 us; speedup vs baseline: 1.0370x; 1.0370x over previous
//
#include <hip/hip_runtime.h>
#include <hip/hip_bf16.h>
#include <math.h>

#define BB 8
#define NN 2048
#define DD 128
#define ALPHA 0.2f
#define LOG2E 1.4426950408889634f

typedef __attribute__((ext_vector_type(8))) short short8;
typedef __attribute__((ext_vector_type(4))) float f32x4;

__device__ inline unsigned short bf16_rne(float v) {
    unsigned int x = __float_as_uint(v);
    unsigned int r = x + 0x7FFFu + ((x >> 16) & 1u);
    return (unsigned short)(r >> 16);
}

// async global->LDS, 16B per lane; LDS dest is wave-uniform base (+lane*16 by HW)
__device__ __forceinline__ void stage16(const void* gsrc, void* lds) {
    __builtin_amdgcn_global_load_lds(
        (const __attribute__((address_space(1))) unsigned int*)gsrc,
        (__attribute__((address_space(3))) unsigned int*)lds, 16, 0, 0);
}

// ---------------- Kernel 0: adj (int32 0/1) -> bitmask, pure HBM stream ----------------
__global__ __launch_bounds__(256) void bitpack_kernel(const int* __restrict__ adj,
                                                      unsigned* __restrict__ bits) {
    unsigned g0 = blockIdx.x * 256 + threadIdx.x;
#pragma unroll
    for (int rep = 0; rep < 2; ++rep) {
        unsigned g = g0 + rep * 524288u;           // 1048576 words total
        const int4* p = reinterpret_cast<const int4*>(adj + (size_t)g * 32);
        int4 v[8];
#pragma unroll
        for (int i = 0; i < 8; ++i) v[i] = p[i];   // 8x16B in flight
        unsigned w = 0;
#pragma unroll
        for (int i = 0; i < 8; ++i) {              // adj values are exactly 0/1
            w |= ((unsigned)v[i].x) << (4 * i);
            w |= ((unsigned)v[i].y) << (4 * i + 1);
            w |= ((unsigned)v[i].z) << (4 * i + 2);
            w |= ((unsigned)v[i].w) << (4 * i + 3);
        }
        bits[g] = w;
    }
}

// ---------------- Kernel 1: f1/f2 scores (pre-scaled by log2e) + bf16 H^T panel ----------------
// Panel layout (per batch): [ks=0..63][n=0..127][c=0..3][e=0..7] bf16, elem = h[ks*32+c*8+e][n]
__global__ __launch_bounds__(256) void pack_kernel(const float* __restrict__ h,
                                                   const float* __restrict__ a1,
                                                   const float* __restrict__ a2,
                                                   float* __restrict__ f1,
                                                   float* __restrict__ f2,
                                                   unsigned short* __restrict__ panel) {
    __shared__ float hs[32][DD];   // 16 KB
    int blk = blockIdx.x;
    int b   = blk >> 6;
    int ks  = blk & 63;
    int r0  = ks * 32;
    int t   = threadIdx.x;

    const float* hb = h + ((size_t)b * NN + r0) * DD;
#pragma unroll
    for (int m = 0; m < 4; ++m) {
        int off = t * 4 + m * 1024;
        *reinterpret_cast<float4*>(&hs[0][0] + off) =
            *reinterpret_cast<const float4*>(hb + off);
    }
    __syncthreads();

    {
        int row = t >> 3, d0 = (t & 7) * 16;
        float s1 = 0.f, s2 = 0.f;
#pragma unroll
        for (int q = 0; q < 4; ++q) {
            float4 hv  = *reinterpret_cast<const float4*>(&hs[row][d0 + q * 4]);
            float4 av1 = *reinterpret_cast<const float4*>(a1 + d0 + q * 4);
            float4 av2 = *reinterpret_cast<const float4*>(a2 + d0 + q * 4);
            s1 += hv.x * av1.x + hv.y * av1.y + hv.z * av1.z + hv.w * av1.w;
            s2 += hv.x * av2.x + hv.y * av2.y + hv.z * av2.z + hv.w * av2.w;
        }
#pragma unroll
        for (int off = 1; off < 8; off <<= 1) {
            s1 += __shfl_xor(s1, off, 64);
            s2 += __shfl_xor(s2, off, 64);
        }
        if ((t & 7) == 0) {
            f1[b * NN + r0 + row] = s1 * LOG2E;   // exp(lrelu(x)) == exp2(lrelu(x*log2e))
            f2[b * NN + r0 + row] = s2 * LOG2E;
        }
    }

    {
        int n = t >> 1;
        size_t base = (((size_t)b * 64 + ks) * 128 + n) * 32;
#pragma unroll
        for (int cc = 0; cc < 2; ++cc) {
            int c = (t & 1) * 2 + cc;
            short8 v;
#pragma unroll
            for (int e = 0; e < 8; ++e) v[e] = (short)bf16_rne(hs[c * 8 + e][n]);
            *reinterpret_cast<short8*>(panel + base + (size_t)c * 8) = v;
        }
    }
}

// ---------------- Kernel 2: LDS-staged MFMA aggregation ----------------
// 512 thr = 8 waves: mt = w>>1 (one 16-row m-tile each), kh = w&1 (K interleave).
// K-step 64 (2 chunks of 32), double-buffered 16KB LDS slices via global_load_lds.
// One barrier per step: sync; stage(next); compute(cur).
__global__ __launch_bounds__(512, 2) void gat_mfma(const unsigned* __restrict__ bits,
                                                   const float* __restrict__ f1,
                                                   const float* __restrict__ f2,
                                                   const unsigned short* __restrict__ panel,
                                                   float* __restrict__ out) {
    __shared__ __align__(16) unsigned char stg[2][16384];   // 32 KB panel slices
    __shared__ __align__(16) float red[4][16][132];         // 33 KB cross-kh reduction
    __shared__ float sden[4][2][16];

    int blk  = blockIdx.x;
    int b    = blk & 7;          // XCD-aligned batch (256 % 8 == 0)
    int tile = blk >> 3;         // 32 tiles of 64 rows per batch
    int i0   = tile * 64;
    int t    = threadIdx.x;
    int w    = t >> 6, l = t & 63;
    int lr   = l & 15, lc = l >> 4;
    int mt   = w >> 1, kh = w & 1;

    const unsigned char* pslice = (const unsigned char*)(panel + (size_t)b * (64 * 128 * 32));
    const float* f2b = f2 + b * NN;
    int irow = i0 + mt * 16 + lr;
    float f1r = f1[b * NN + irow];
    const unsigned* brow = bits + ((size_t)(b * NN + irow) << 6);

    f32x4 acc[8];
#pragma unroll
    for (int nt = 0; nt < 8; ++nt) acc[nt] = (f32x4){0.f, 0.f, 0.f, 0.f};
    f32x4 accd = (f32x4){0.f, 0.f, 0.f, 0.f};

    short8 ones;
#pragma unroll
    for (int e = 0; e < 8; ++e) ones[e] = (short)0x3F80;   // bf16 1.0

    // staging addresses: wave w, round r covers bytes [r*8192 + w*1024, +1KB)
    int soff = w * 1024 + l * 16;          // global: per-lane
    int doff = w * 1024;                   // LDS: wave-uniform

    // stage step 0 into buf 0
    stage16(pslice + soff, stg[0] + doff);
    stage16(pslice + 8192 + soff, stg[0] + 8192 + doff);

    // per-step W-gen prefetch state (chunk c = 2s + kh)
    unsigned bcur = brow[kh];
    float4 g0c = *reinterpret_cast<const float4*>(f2b + kh * 32 + lc * 8);
    float4 g1c = *reinterpret_cast<const float4*>(f2b + kh * 32 + lc * 8 + 4);

    const unsigned char* myfrag0 = &stg[0][0] + kh * 8192 + lr * 64 + lc * 16;
    const unsigned char* myfrag1 = &stg[1][0] + kh * 8192 + lr * 64 + lc * 16;

#pragma unroll 2
    for (int s = 0; s < 32; ++s) {
        int cur = s & 1;
        __syncthreads();   // staged buf[cur] ready (vmcnt drained); all waves done with buf[cur^1]

        if (s < 31) {
            const unsigned char* src = pslice + (size_t)(s + 1) * 16384;
            unsigned char* dst = stg[cur ^ 1];
            stage16(src + soff, dst + doff);
            stage16(src + 8192 + soff, dst + 8192 + doff);
        }

        unsigned bs = bcur >> (lc * 8);
        float4 g0 = g0c, g1 = g1c;
        if (s < 31) {   // prefetch next step's bits/f2 (chunk 2(s+1)+kh)
            int cn = 2 * (s + 1) + kh;
            bcur = brow[cn];
            g0c = *reinterpret_cast<const float4*>(f2b + cn * 32 + lc * 8);
            g1c = *reinterpret_cast<const float4*>(f2b + cn * 32 + lc * 8 + 4);
        }

        float f2v[8] = {g0.x, g0.y, g0.z, g0.w, g1.x, g1.y, g1.z, g1.w};
        float wv[8];
#pragma unroll
        for (int e = 0; e < 8; ++e) {
            float x  = f1r + f2v[e];
            float ee = fmaxf(x, ALPHA * x);
            float gv = __builtin_amdgcn_exp2f(ee);
            wv[e] = ((bs >> e) & 1u) ? gv : 0.f;
        }
        union { short8 s8; __hip_bfloat162 h2[4]; } u;
#pragma unroll
        for (int p = 0; p < 4; ++p)
            u.h2[p] = __float22bfloat162_rn(make_float2(wv[2 * p], wv[2 * p + 1]));

        const unsigned char* frag = cur ? myfrag1 : myfrag0;
#pragma unroll
        for (int nt = 0; nt < 8; ++nt) {
            short8 bfv = *reinterpret_cast<const short8*>(frag + nt * 1024);
            acc[nt] = __builtin_amdgcn_mfma_f32_16x16x32_bf16(u.s8, bfv, acc[nt], 0, 0, 0);
        }
        accd = __builtin_amdgcn_mfma_f32_16x16x32_bf16(u.s8, ones, accd, 0, 0, 0);
    }

    // denominator partials: D rows lc*4+r (uniform over cols); lane lr==0 writes
    if (lr == 0) {
#pragma unroll
        for (int r = 0; r < 4; ++r) sden[mt][kh][lc * 4 + r] = accd[r];
    }

    // cross-kh reduction in red[mt]
    if (kh == 0) {
#pragma unroll
        for (int nt = 0; nt < 8; ++nt) {
            float* p = &red[mt][lc * 4][nt * 16 + lr];
#pragma unroll
            for (int r = 0; r < 4; ++r) p[r * 132] = acc[nt][r];
        }
    }
    __syncthreads();
    if (kh == 1) {
#pragma unroll
        for (int nt = 0; nt < 8; ++nt) {
            float* p = &red[mt][lc * 4][nt * 16 + lr];
#pragma unroll
            for (int r = 0; r < 4; ++r) p[r * 132] += acc[nt][r];
        }
    }
    __syncthreads();

    // epilogue: thread t -> row t>>3 (0..63), cols (t&7)*16..+15
    {
        int row = t >> 3, col0 = (t & 7) * 16;
        int rmt = row >> 4, rloc = row & 15;
        float den = sden[rmt][0][rloc] + sden[rmt][1][rloc];
        float inv = 1.0f / den;
        float* ob = out + ((size_t)b * NN + i0 + row) * DD;
#pragma unroll
        for (int q = 0; q < 4; ++q) {
            int col = col0 + q * 4;
            float4 v = *reinterpret_cast<const float4*>(&red[rmt][rloc][col]);
            float r0 = v.x * inv, r1 = v.y * inv, r2 = v.z * inv, r3 = v.w * inv;
            r0 = (r0 > 0.f) ? r0 : expm1f(r0);
            r1 = (r1 > 0.f) ? r1 : expm1f(r1);
            r2 = (r2 > 0.f) ? r2 : expm1f(r2);
            r3 = (r3 > 0.f) ? r3 : expm1f(r3);
            *reinterpret_cast<float4*>(ob + col) = make_float4(r0, r1, r2, r3);
        }
    }
}

extern "C" void kernel_launch(void* const* d_in, const int* in_sizes, int n_in,
                              void* d_out, int out_size, void* d_ws, size_t ws_size,
                              hipStream_t stream) {
    const float* h   = (const float*)d_in[0];
    const int*   adj = (const int*)d_in[1];
    const float* a1  = (const float*)d_in[2];
    const float* a2  = (const float*)d_in[3];
    float* out = (float*)d_out;

    float* f1 = (float*)d_ws;                                   // 16384 floats
    float* f2 = f1 + BB * NN;                                   // 16384 floats
    unsigned short* panel = (unsigned short*)(f2 + BB * NN);    // 4 MB
    unsigned* bits = (unsigned*)(panel + (size_t)BB * 64 * 128 * 32);  // 4 MB

    bitpack_kernel<<<2048, 256, 0, stream>>>(adj, bits);
    pack_kernel<<<BB * 64, 256, 0, stream>>>(h, a1, a2, f1, f2, panel);
    gat_mfma<<<BB * 32, 512, 0, stream>>>(bits, f1, f2, panel, out);
}